// Round 9
// baseline (730.211 us; speedup 1.0000x reference)
//
#include <hip/hip_runtime.h>

#define CI   128
#define TT   8192
#define CO   256
#define KW   9
#define NQ   5
#define PADL 4
#define KDIM (CI*KW)       // 1152
#define NSTEP 36           // K32 steps per q
#define NF (NQ*NSTEP)      // 180
#define BCO  128
#define BT   128
#define XROWS 136
#define XP2  128           // 256B rows, 16 x 16B slots, XOR-swizzled by row&7

typedef __attribute__((ext_vector_type(8))) short short8;
typedef __attribute__((ext_vector_type(4))) float float4v;

static __device__ __forceinline__ short f2bf(float f) {
  union { float f; unsigned u; } c; c.f = f;
  unsigned u = c.u;
  return (short)((u + 0x7FFFu + ((u >> 16) & 1u)) >> 16);  // RNE
}

static __device__ __forceinline__ float tanh_fast(float z) {
  float e = __expf(2.f * z);
  return (e - 1.f) / (e + 1.f);
}

// ---- kernel 1: pack conv_weights (CO,CI,KW,NQ) fp32 into per-lane fragment
// stream (unchanged from R8): coalesced 1KB lines per (fi, wm, m), L2-resident.
__global__ void selfonn_wpack(const float* __restrict__ w, short* __restrict__ wpk, int n) {
  int o = blockIdx.x * 256 + threadIdx.x;
  if (o >= n) return;
  int j    = o & 7;
  int lane = (o >> 3) & 63;
  int m    = (o >> 9) & 3;
  int wm   = (o >> 11) & 1;
  int ft   = o >> 12;          // 0..2*NF-1
  int ch   = ft / NF;
  int fi   = ft - ch * NF;
  int q    = fi / NSTEP;
  int step = fi - q * NSTEP;
  int k    = step >> 2;
  int cib  = step & 3;
  int l15  = lane & 15;
  int lg   = lane >> 4;
  int co   = ch * 128 + wm * 64 + m * 16 + l15;
  int ci   = cib * 32 + lg * 8 + j;
  wpk[o] = f2bf(w[((co * CI + ci) * KW + k) * NQ + q]);
}

// ---- kernel 2: fused implicit-GEMM conv + nonlinearities + weighted sum ----
// Barrier-free main loop; weights stream global->VGPR (L2-resident) depth-1;
// x tile in XOR-swizzled LDS (conflict-free b128 reads); 4 blocks/CU.
__global__ __launch_bounds__(256, 4) void selfonn_main(
    const float* __restrict__ x, const short* __restrict__ wpk,
    const float* __restrict__ probs, float* __restrict__ out) {

  __shared__ __align__(16) short xs[XROWS * XP2];     // 34816 B
  __shared__ float opw[BCO][NQ];                      // 2560 B

  const int tid  = threadIdx.x;
  const int lane = tid & 63;
  const int wid  = tid >> 6;   // 0..3
  const int wm   = wid >> 1;   // co half
  const int wt   = wid & 1;    // t half
  const int l15  = lane & 15;
  const int lg   = lane >> 4;  // 0..3
  const int b    = blockIdx.z;
  const int ch   = blockIdx.y;          // co 128-half of 256
  const int co0  = ch * BCO;
  const int t0   = blockIdx.x * BT;

  // operator softmax -> LDS
  if (tid < BCO) {
    float p[NQ];
    float mx = -1e30f;
    #pragma unroll
    for (int j = 0; j < NQ; ++j) { p[j] = probs[(co0 + tid) * NQ + j]; mx = fmaxf(mx, p[j]); }
    float s = 0.f;
    #pragma unroll
    for (int j = 0; j < NQ; ++j) { p[j] = __expf(p[j] - mx); s += p[j]; }
    float inv = 1.0f / s;
    #pragma unroll
    for (int j = 0; j < NQ; ++j) opw[tid][j] = p[j] * inv;
  }

  // stage x tile once (t-transposed, bf16, XOR-swizzled):
  // xs[row*128 + ((ci>>3 ^ (row&7))<<3) + (ci&7)] = x[b][ci][t0-4+row]
  const float* xb = x + (size_t)b * CI * TT;
  #pragma unroll
  for (int it = 0; it < 17; ++it) {
    int cell = tid + it * 256;          // 0..4351
    int ci = cell & (CI - 1);
    int tc = cell >> 7;                 // 0..33
    int tg = t0 - PADL + tc * 4;
    float4v v = {0.f, 0.f, 0.f, 0.f};
    if (tg >= 0 && tg <= TT - 4)
      v = *(const float4v*)(xb + (size_t)ci * TT + tg);
    int tl = tc * 4;
    int chi = ci >> 3, clo = ci & 7;
    #pragma unroll
    for (int j = 0; j < 4; ++j) {
      int row = tl + j;
      xs[row * XP2 + ((chi ^ (row & 7)) << 3) + clo] = f2bf(v[j]);
    }
  }

  // B-frag row bases (shorts): row_n = wt*64 + n*16 + l15 (+k at runtime)
  int bro[4];
  #pragma unroll
  for (int n = 0; n < 4; ++n)
    bro[n] = (wt * 64 + n * 16 + l15) * XP2;

  // wave's packed-weight stream pointer (shorts): fi=0 frag base
  const short* wp = wpk + ((size_t)(ch * NF) * 2 + wm) * 2048 + lane * 8;

  float4v oacc[4][4];
  float4v acc[4][4];
  #pragma unroll
  for (int m = 0; m < 4; ++m)
    #pragma unroll
    for (int n = 0; n < 4; ++n) {
      oacc[m][n] = (float4v){0.f, 0.f, 0.f, 0.f};
      acc[m][n]  = (float4v){0.f, 0.f, 0.f, 0.f};
    }

  __syncthreads();   // xs/opw ready; no further barriers

  short8 WA[4], WB[4], BA[4], BB[4];
  // prologue: frags(0): sq=0 -> k=0, slot=lg, swz = (lg ^ (l15&7))
  {
    const short* xp = &xs[0] + ((lg ^ (l15 & 7)) << 3);
    #pragma unroll
    for (int n = 0; n < 4; ++n) BA[n] = *(const short8*)(xp + bro[n]);
    #pragma unroll
    for (int m = 0; m < 4; ++m) WA[m] = *(const short8*)(wp + m * 512);
  }

  int sq = 0, q = 0;

  #define STEP(CW, CB, NW, NB, DOPF, DOEPI)                            \
    {                                                                  \
      if (DOPF) {                                                      \
        /* prefetch weight frags(fi+1): linear stream, +8KB per fi */  \
        wp += 4096;                                                    \
        _Pragma("unroll") for (int m = 0; m < 4; ++m)                  \
          NW[m] = *(const short8*)(wp + m * 512);                      \
        /* prefetch B frags(fi+1) from swizzled xs */                  \
        int sqn = (sq == NSTEP - 1) ? 0 : sq + 1;                      \
        int kn  = sqn >> 2;                                            \
        int swz = ((((sqn & 3) << 2) + lg) ^ ((l15 + kn) & 7)) << 3;   \
        const short* xp = &xs[0] + kn * XP2 + swz;                     \
        _Pragma("unroll") for (int n = 0; n < 4; ++n)                  \
          NB[n] = *(const short8*)(xp + bro[n]);                       \
      }                                                                \
      __builtin_amdgcn_s_setprio(1);                                   \
      _Pragma("unroll") for (int m = 0; m < 4; ++m)                    \
        _Pragma("unroll") for (int n = 0; n < 4; ++n)                  \
          acc[m][n] = __builtin_amdgcn_mfma_f32_16x16x32_bf16(         \
              CW[m], CB[n], acc[m][n], 0, 0, 0);                       \
      __builtin_amdgcn_s_setprio(0);                                   \
      if (DOEPI && sq == NSTEP - 1) {                                  \
        _Pragma("unroll") for (int m = 0; m < 4; ++m) {                \
          _Pragma("unroll") for (int jj = 0; jj < 4; ++jj) {           \
            int co_l = wm * 64 + m * 16 + lg * 4 + jj;                 \
            float wqv = opw[co_l][q];                                  \
            _Pragma("unroll") for (int n = 0; n < 4; ++n) {            \
              float z = acc[m][n][jj];                                 \
              float f;                                                 \
              if (q == 0)      f = z;                                  \
              else if (q == 1) f = __sinf(z);                          \
              else if (q == 2) f = __cosf(z);                          \
              else if (q == 3) f = tanh_fast(z);                       \
              else             f = __expf(fminf(fmaxf(z, -8.f), 8.f)); \
              oacc[m][n][jj] += wqv * f;                               \
              acc[m][n][jj] = 0.f;                                     \
            }                                                          \
          }                                                            \
        }                                                              \
        ++q; sq = 0;                                                   \
      } else {                                                         \
        ++sq;                                                          \
      }                                                                \
    }

  // fi = 0..177 (epilogues at fi = 35,71,107,143 land on the B copy)
  for (int u = 0; u < 89; ++u) {
    STEP(WA, BA, WB, BB, 1, 0)
    STEP(WB, BB, WA, BA, 1, 1)
  }
  // fi = 178 (prefetch 179), fi = 179 (no prefetch; epilogue q=4)
  STEP(WA, BA, WB, BB, 1, 0)
  STEP(WB, BB, WA, BA, 0, 1)
  #undef STEP

  // store (B, CO, T) fp32
  float* ob = out + (size_t)(b * CO + co0) * TT;
  #pragma unroll
  for (int m = 0; m < 4; ++m) {
    #pragma unroll
    for (int jj = 0; jj < 4; ++jj) {
      int co_l = wm * 64 + m * 16 + lg * 4 + jj;
      int tcol = t0 + wt * 64 + l15;
      float* orow = ob + (size_t)co_l * TT + tcol;
      #pragma unroll
      for (int n = 0; n < 4; ++n)
        orow[n * 16] = oacc[m][n][jj];
    }
  }
}

extern "C" void kernel_launch(void* const* d_in, const int* in_sizes, int n_in,
                              void* d_out, int out_size, void* d_ws, size_t ws_size,
                              hipStream_t stream) {
  const float* x     = (const float*)d_in[0];
  const float* w     = (const float*)d_in[1];
  const float* probs = (const float*)d_in[2];
  float* out = (float*)d_out;
  short* wpk = (short*)d_ws;   // NQ*CO*KDIM*2 = 2.95 MB

  int nw = NQ * CO * KDIM;     // 1,474,560
  selfonn_wpack<<<dim3((nw + 255) / 256), 256, 0, stream>>>(w, wpk, nw);

  dim3 grid(TT / BT, CO / BCO, 16);
  selfonn_main<<<grid, 256, 0, stream>>>(x, wpk, probs, out);
}

// Round 10
// 345.834 us; speedup vs baseline: 2.1114x; 2.1114x over previous
//
#include <hip/hip_runtime.h>

#define CI   128
#define TT   8192
#define CO   256
#define KW   9
#define NQ   5
#define PADL 4
#define KDIM (CI*KW)       // 1152
#define NSTEP 36           // K32 steps per q
#define NF (NQ*NSTEP)      // 180
#define BCO  128
#define BT   128
#define XROWS 136
#define XPITCH 136         // 272B rows: 17 x 16B granules (odd) -> octet-clean b128 reads

typedef __attribute__((ext_vector_type(8))) short short8;
typedef __attribute__((ext_vector_type(4))) float float4v;

static __device__ __forceinline__ short f2bf(float f) {
  union { float f; unsigned u; } c; c.f = f;
  unsigned u = c.u;
  return (short)((u + 0x7FFFu + ((u >> 16) & 1u)) >> 16);  // RNE
}

static __device__ __forceinline__ float tanh_fast(float z) {
  float e = __expf(2.f * z);
  return (e - 1.f) / (e + 1.f);
}

// ---- kernel 1: pack conv_weights (CO,CI,KW,NQ) fp32 into per-lane fragment
// stream: coalesced 1KB lines per (fi, wm, m), L2-resident (2.95MB < 4MB/XCD).
__global__ void selfonn_wpack(const float* __restrict__ w, short* __restrict__ wpk, int n) {
  int o = blockIdx.x * 256 + threadIdx.x;
  if (o >= n) return;
  int j    = o & 7;
  int lane = (o >> 3) & 63;
  int m    = (o >> 9) & 3;
  int wm   = (o >> 11) & 1;
  int ft   = o >> 12;          // 0..2*NF-1
  int ch   = ft / NF;
  int fi   = ft - ch * NF;
  int q    = fi / NSTEP;
  int step = fi - q * NSTEP;
  int k    = step >> 2;
  int cib  = step & 3;
  int l15  = lane & 15;
  int lg   = lane >> 4;
  int co   = ch * 128 + wm * 64 + m * 16 + l15;
  int ci   = cib * 32 + lg * 8 + j;
  wpk[o] = f2bf(w[((co * CI + ci) * KW + k) * NQ + q]);
}

// ---- kernel 2: fused implicit-GEMM conv + nonlinearities + weighted sum ----
// Barrier-free main loop; weights stream global->VGPR (L2-resident) with a
// depth-2 (ring-3) prefetch; x tile static in LDS; 2 blocks/CU.
__global__ __launch_bounds__(256, 2) void selfonn_main(
    const float* __restrict__ x, const short* __restrict__ wpk,
    const float* __restrict__ probs, float* __restrict__ out) {

  __shared__ __align__(16) short xs[XROWS][XPITCH];   // 36992 B
  __shared__ float opw[BCO][NQ];                      // 2560 B

  const int tid  = threadIdx.x;
  const int lane = tid & 63;
  const int wid  = tid >> 6;   // 0..3
  const int wm   = wid >> 1;   // co half
  const int wt   = wid & 1;    // t half
  const int l15  = lane & 15;
  const int lg   = lane >> 4;  // 0..3
  const int b    = blockIdx.z;
  const int ch   = blockIdx.y;          // co 128-half of 256
  const int co0  = ch * BCO;
  const int t0   = blockIdx.x * BT;

  // operator softmax -> LDS
  if (tid < BCO) {
    float p[NQ];
    float mx = -1e30f;
    #pragma unroll
    for (int j = 0; j < NQ; ++j) { p[j] = probs[(co0 + tid) * NQ + j]; mx = fmaxf(mx, p[j]); }
    float s = 0.f;
    #pragma unroll
    for (int j = 0; j < NQ; ++j) { p[j] = __expf(p[j] - mx); s += p[j]; }
    float inv = 1.0f / s;
    #pragma unroll
    for (int j = 0; j < NQ; ++j) opw[tid][j] = p[j] * inv;
  }

  // stage x tile once (t-transposed, bf16): xs[tl][ci] = x[b][ci][t0-4+tl]
  const float* xb = x + (size_t)b * CI * TT;
  #pragma unroll
  for (int it = 0; it < 17; ++it) {
    int cell = tid + it * 256;          // 0..4351
    int ci = cell & (CI - 1);
    int tc = cell >> 7;                 // 0..33
    int tg = t0 - PADL + tc * 4;
    float4v v = {0.f, 0.f, 0.f, 0.f};
    if (tg >= 0 && tg <= TT - 4)
      v = *(const float4v*)(xb + (size_t)ci * TT + tg);
    int tl = tc * 4;
    xs[tl + 0][ci] = f2bf(v[0]);
    xs[tl + 1][ci] = f2bf(v[1]);
    xs[tl + 2][ci] = f2bf(v[2]);
    xs[tl + 3][ci] = f2bf(v[3]);
  }

  // B-frag LDS offsets (shorts)
  int bfo[4];
  #pragma unroll
  for (int n = 0; n < 4; ++n)
    bfo[n] = (wt * 64 + n * 16 + l15) * XPITCH + (lg << 3);

  // wave's packed-weight stream pointer (shorts): fi=0 frag base
  const short* wp = wpk + ((size_t)(ch * NF) * 2 + wm) * 2048 + lane * 8;

  float4v oacc[4][4];
  float4v acc[4][4];
  #pragma unroll
  for (int m = 0; m < 4; ++m)
    #pragma unroll
    for (int n = 0; n < 4; ++n) {
      oacc[m][n] = (float4v){0.f, 0.f, 0.f, 0.f};
      acc[m][n]  = (float4v){0.f, 0.f, 0.f, 0.f};
    }

  __syncthreads();   // xs/opw ready; no further barriers

  short8 W0[4], W1[4], W2[4], BA[4], BB[4];
  // prologue: W(0)->W0, W(1)->W1, B(0)->BA
  #pragma unroll
  for (int m = 0; m < 4; ++m) W0[m] = *(const short8*)(wp + m * 512);
  #pragma unroll
  for (int m = 0; m < 4; ++m) W1[m] = *(const short8*)(wp + 4096 + m * 512);
  wp += 8192;    // now points at fi=2's frag base
  #pragma unroll
  for (int n = 0; n < 4; ++n) BA[n] = *(const short8*)(&xs[0][0] + bfo[n]);

  int sq = 0, q = 0;

  #define STEP(CW, CB, NW, NB, PFW, PFB, EPI)                          \
    {                                                                  \
      if (PFW) {                                                       \
        /* prefetch weight frags(fi+2): linear stream, 8KB per fi */   \
        _Pragma("unroll") for (int m = 0; m < 4; ++m)                  \
          NW[m] = *(const short8*)(wp + m * 512);                      \
        wp += 4096;                                                    \
      }                                                                \
      if (PFB) {                                                       \
        /* prefetch B frags(fi+1) from static xs */                    \
        int sqn = (sq == NSTEP - 1) ? 0 : sq + 1;                      \
        const short* xp = &xs[0][0] + (sqn >> 2) * XPITCH + ((sqn & 3) << 5); \
        _Pragma("unroll") for (int n = 0; n < 4; ++n)                  \
          NB[n] = *(const short8*)(xp + bfo[n]);                       \
      }                                                                \
      __builtin_amdgcn_s_setprio(1);                                   \
      _Pragma("unroll") for (int m = 0; m < 4; ++m)                    \
        _Pragma("unroll") for (int n = 0; n < 4; ++n)                  \
          acc[m][n] = __builtin_amdgcn_mfma_f32_16x16x32_bf16(         \
              CW[m], CB[n], acc[m][n], 0, 0, 0);                       \
      __builtin_amdgcn_s_setprio(0);                                   \
      if (EPI && sq == NSTEP - 1) {                                    \
        _Pragma("unroll") for (int m = 0; m < 4; ++m) {                \
          _Pragma("unroll") for (int jj = 0; jj < 4; ++jj) {           \
            int co_l = wm * 64 + m * 16 + lg * 4 + jj;                 \
            float wqv = opw[co_l][q];                                  \
            _Pragma("unroll") for (int n = 0; n < 4; ++n) {            \
              float z = acc[m][n][jj];                                 \
              float f;                                                 \
              if (q == 0)      f = z;                                  \
              else if (q == 1) f = __sinf(z);                          \
              else if (q == 2) f = __cosf(z);                          \
              else if (q == 3) f = tanh_fast(z);                       \
              else             f = __expf(fminf(fmaxf(z, -8.f), 8.f)); \
              oacc[m][n][jj] += wqv * f;                               \
              acc[m][n][jj] = 0.f;                                     \
            }                                                          \
          }                                                            \
        }                                                              \
        ++q; sq = 0;                                                   \
      } else {                                                         \
        ++sq;                                                          \
      }                                                                \
    }

  // 6-step unroll: W sets period-3, B sets period-2; epilogues (sq==35)
  // always land at position 5 (35,71,107,143,179 all == 5 mod 6).
  for (int u = 0; u < 29; ++u) {        // fi = 0..173
    STEP(W0, BA, W2, BB, 1, 1, 0)
    STEP(W1, BB, W0, BA, 1, 1, 0)
    STEP(W2, BA, W1, BB, 1, 1, 0)
    STEP(W0, BB, W2, BA, 1, 1, 0)
    STEP(W1, BA, W0, BB, 1, 1, 0)
    STEP(W2, BB, W1, BA, 1, 1, 1)
  }
  // tail fi = 174..179
  STEP(W0, BA, W2, BB, 1, 1, 0)   // 174: prefetch W(176), B(175)
  STEP(W1, BB, W0, BA, 1, 1, 0)   // 175: prefetch W(177), B(176)
  STEP(W2, BA, W1, BB, 1, 1, 0)   // 176: prefetch W(178), B(177)
  STEP(W0, BB, W2, BA, 1, 1, 0)   // 177: prefetch W(179), B(178)
  STEP(W1, BA, W0, BB, 0, 1, 0)   // 178: prefetch B(179) only
  STEP(W2, BB, W1, BA, 0, 0, 1)   // 179: epilogue q=4
  #undef STEP

  // store (B, CO, T) fp32
  float* ob = out + (size_t)(b * CO + co0) * TT;
  #pragma unroll
  for (int m = 0; m < 4; ++m) {
    #pragma unroll
    for (int jj = 0; jj < 4; ++jj) {
      int co_l = wm * 64 + m * 16 + lg * 4 + jj;
      int tcol = t0 + wt * 64 + l15;
      float* orow = ob + (size_t)co_l * TT + tcol;
      #pragma unroll
      for (int n = 0; n < 4; ++n)
        orow[n * 16] = oacc[m][n][jj];
    }
  }
}

extern "C" void kernel_launch(void* const* d_in, const int* in_sizes, int n_in,
                              void* d_out, int out_size, void* d_ws, size_t ws_size,
                              hipStream_t stream) {
  const float* x     = (const float*)d_in[0];
  const float* w     = (const float*)d_in[1];
  const float* probs = (const float*)d_in[2];
  float* out = (float*)d_out;
  short* wpk = (short*)d_ws;   // NQ*CO*KDIM*2 = 2.95 MB

  int nw = NQ * CO * KDIM;     // 1,474,560
  selfonn_wpack<<<dim3((nw + 255) / 256), 256, 0, stream>>>(w, wpk, nw);

  dim3 grid(TT / BT, CO / BCO, 16);
  selfonn_main<<<grid, 256, 0, stream>>>(x, wpk, probs, out);
}